// Round 3
// baseline (1674.475 us; speedup 1.0000x reference)
//
#include <hip/hip_runtime.h>

#define F_IN 256
#define SC_CHUNK 16384

// ---------------- GEMM: h = x @ W  (M x 256) @ (256 x 64) -> (M x 64) --------
__global__ __launch_bounds__(256) void gemm_xw_kernel(
    const float* __restrict__ x, const float* __restrict__ W,
    float* __restrict__ h, int M) {
  __shared__ float As[32][68];
  __shared__ float Bs[32][64];
  const int t = threadIdx.x;
  const int brow = blockIdx.x * 64;
  const int tc = t & 15;
  const int tr = t >> 4;
  float acc[4][4] = {{0.f}};

  for (int k0 = 0; k0 < F_IN; k0 += 32) {
    {
      const int m = t >> 3;
      const int kq = (t & 7) << 2;
#pragma unroll
      for (int half = 0; half < 2; ++half) {
        const int mm = m + half * 32;
        const int row = brow + mm;
        float4 v = make_float4(0.f, 0.f, 0.f, 0.f);
        if (row < M) v = *(const float4*)(x + (size_t)row * F_IN + k0 + kq);
        As[kq + 0][mm] = v.x;
        As[kq + 1][mm] = v.y;
        As[kq + 2][mm] = v.z;
        As[kq + 3][mm] = v.w;
      }
#pragma unroll
      for (int half = 0; half < 2; ++half) {
        const int i = t + half * 256;
        const int kb = i >> 4;
        const int nq = (i & 15) << 2;
        *(float4*)&Bs[kb][nq] = *(const float4*)(W + (size_t)(k0 + kb) * 64 + nq);
      }
    }
    __syncthreads();
#pragma unroll
    for (int k = 0; k < 32; ++k) {
      const float4 a = *(const float4*)&As[k][tr << 2];
      const float4 b = *(const float4*)&Bs[k][tc << 2];
      const float av[4] = {a.x, a.y, a.z, a.w};
      const float bv[4] = {b.x, b.y, b.z, b.w};
#pragma unroll
      for (int i = 0; i < 4; ++i)
#pragma unroll
        for (int j = 0; j < 4; ++j) acc[i][j] += av[i] * bv[j];
    }
    __syncthreads();
  }
#pragma unroll
  for (int i = 0; i < 4; ++i) {
    const int row = brow + (tr << 2) + i;
    if (row < M) {
      float4 v = make_float4(acc[i][0], acc[i][1], acc[i][2], acc[i][3]);
      *(float4*)(h + (size_t)row * 64 + (tc << 2)) = v;
    }
  }
}

// ---------------- coarse histogram over dst>>8 -------------------------------
__global__ __launch_bounds__(256) void hist_coarse_kernel(
    const int* __restrict__ dst_arr, int* __restrict__ bucketCount,
    int E, int NBK) {
  __shared__ int hist[512];
  const int t = threadIdx.x;
  for (int i = t; i < NBK; i += 256) hist[i] = 0;
  __syncthreads();
  const int base = blockIdx.x * SC_CHUNK;
  const int end = min(base + SC_CHUNK, E);
  for (int i = base + t; i < end; i += 256)
    atomicAdd(&hist[dst_arr[i] >> 8], 1);
  __syncthreads();
  for (int i = t; i < NBK; i += 256)
    if (hist[i]) atomicAdd(&bucketCount[i], hist[i]);
}

// ---------------- scan bucket counts (NBK <= 512) ----------------------------
__global__ __launch_bounds__(512) void scan_buckets_kernel(
    const int* __restrict__ bucketCount, int* __restrict__ bucketStart,
    int* __restrict__ bucketCursor, int NBK) {
  __shared__ int s[512];
  const int t = threadIdx.x;
  const int v = (t < NBK) ? bucketCount[t] : 0;
  s[t] = v;
  __syncthreads();
#pragma unroll
  for (int off = 1; off < 512; off <<= 1) {
    int add = (t >= off) ? s[t - off] : 0;
    __syncthreads();
    s[t] += add;
    __syncthreads();
  }
  if (t < NBK) {
    const int excl = s[t] - v;
    bucketStart[t] = excl;
    bucketCursor[t] = excl;
  }
  if (t == NBK - 1) bucketStart[NBK] = s[t];
}

// ---------------- coarse scatter: es2 grouped by bucket ----------------------
__global__ __launch_bounds__(256) void scatter_coarse_kernel(
    const int* __restrict__ src_arr, const int* __restrict__ dst_arr,
    int* __restrict__ bucketCursor, int2* __restrict__ es2, int E, int NBK) {
  __shared__ int hist[512];
  __shared__ int cur[512];
  const int t = threadIdx.x;
  for (int i = t; i < NBK; i += 256) hist[i] = 0;
  __syncthreads();
  const int base = blockIdx.x * SC_CHUNK;
  const int end = min(base + SC_CHUNK, E);
  for (int i = base + t; i < end; i += 256)
    atomicAdd(&hist[dst_arr[i] >> 8], 1);
  __syncthreads();
  for (int i = t; i < NBK; i += 256)
    cur[i] = hist[i] ? atomicAdd(&bucketCursor[i], hist[i]) : 0;
  __syncthreads();
  for (int i = base + t; i < end; i += 256) {
    const int s = src_arr[i];
    const int d = dst_arr[i];
    const int pos = atomicAdd(&cur[d >> 8], 1);
    es2[pos] = make_int2(s, d);
  }
}

// ---------------- per-bucket degrees -> dinvp --------------------------------
__global__ __launch_bounds__(256) void deg_fine_kernel(
    const int2* __restrict__ es2, const int* __restrict__ bucketStart,
    float* __restrict__ dinvp, int N) {
  __shared__ int hist[256];
  const int t = threadIdx.x;
  hist[t] = 0;
  __syncthreads();
  const int b = blockIdx.x;
  const int start = bucketStart[b], end = bucketStart[b + 1];
  for (int i = start + t; i < end; i += 256)
    atomicAdd(&hist[es2[i].y & 255], 1);
  __syncthreads();
  const int node = b * 256 + t;
  if (node < N) dinvp[node] = rsqrtf((float)(hist[t] + 1));  // +1 self-loop
}

// ---------------- fused aggregation + MLP, one block per bucket --------------
__global__ __launch_bounds__(512) void agg_mlp_kernel(
    const float* __restrict__ h, const int2* __restrict__ es2,
    const int* __restrict__ bucketStart, const float* __restrict__ dinvp,
    const float* __restrict__ bg,
    const float* __restrict__ W1, const float* __restrict__ b1,
    const float* __restrict__ W2, const float* __restrict__ b2,
    const float* __restrict__ W3, const float* __restrict__ b3,
    float* __restrict__ out, int N) {
  __shared__ float acc[256 * 65];   // [local_node][feat], pad 65 vs bank conflicts
  __shared__ float W1T[32][64];
  __shared__ float W2T[16][32];
  __shared__ float W3T[10][16];
  __shared__ float b1s[32], b2s[16], b3s[10], bgs[64];
  const int t = threadIdx.x;
  for (int i = t; i < 256 * 65; i += 512) acc[i] = 0.f;
  for (int i = t; i < 2048; i += 512) W1T[i >> 6][i & 63] = W1[(i & 63) * 32 + (i >> 6)];
  if (t < 512) { const int i = t; if (i < 512) W2T[i >> 5][i & 31] = W2[(i & 31) * 16 + (i >> 5)]; }
  if (t < 160) W3T[t >> 4][t & 15] = W3[(t & 15) * 10 + (t >> 4)];
  if (t < 64) bgs[t] = bg[t];
  if (t < 32) b1s[t] = b1[t];
  if (t < 16) b2s[t] = b2[t];
  if (t < 10) b3s[t] = b3[t];
  __syncthreads();

  const int b = blockIdx.x;
  const int start = bucketStart[b], end = bucketStart[b + 1];
  const int wid = t >> 6;     // 8 waves
  const int lane = t & 63;    // lane == feature

#pragma unroll 4
  for (int i = start + wid; i < end; i += 8) {
    const int2 e = es2[i];                       // broadcast load
    const float w = dinvp[e.x];                  // broadcast load
    const float hv = h[(size_t)e.x * 64 + lane]; // coalesced 256B row
    atomicAdd(&acc[(e.y & 255) * 65 + lane], w * hv);
  }
  __syncthreads();

  if (t < 256) {
    const int node = b * 256 + t;
    if (node < N) {
      const float di = dinvp[node];
      const float d2 = di * di;
      const float* hrow = h + (size_t)node * 64;
      float* arow = acc + t * 65;
      // g = relu(di * sum + di^2 * h_own + bias), stored back into acc row
#pragma unroll
      for (int f = 0; f < 64; f += 4) {
        const float4 hv = *(const float4*)(hrow + f);
        arow[f + 0] = fmaxf(arow[f + 0] * di + d2 * hv.x + bgs[f + 0], 0.f);
        arow[f + 1] = fmaxf(arow[f + 1] * di + d2 * hv.y + bgs[f + 1], 0.f);
        arow[f + 2] = fmaxf(arow[f + 2] * di + d2 * hv.z + bgs[f + 2], 0.f);
        arow[f + 3] = fmaxf(arow[f + 3] * di + d2 * hv.w + bgs[f + 3], 0.f);
      }

      float h1[32];
#pragma unroll
      for (int j = 0; j < 32; ++j) {
        float s = b1s[j];
#pragma unroll
        for (int k = 0; k < 64; k += 4) {
          const float4 w = *(const float4*)&W1T[j][k];
          const float4 g = *(const float4*)(arow + k);
          s += g.x * w.x + g.y * w.y + g.z * w.z + g.w * w.w;
        }
        h1[j] = fmaxf(s, 0.f);
      }

      float h2[16];
#pragma unroll
      for (int j = 0; j < 16; ++j) {
        float s = b2s[j];
#pragma unroll
        for (int k = 0; k < 32; k += 4) {
          const float4 w = *(const float4*)&W2T[j][k];
          s += h1[k] * w.x + h1[k + 1] * w.y + h1[k + 2] * w.z + h1[k + 3] * w.w;
        }
        h2[j] = fmaxf(s, 0.f);
      }

#pragma unroll
      for (int j = 0; j < 10; ++j) {
        float s = b3s[j];
#pragma unroll
        for (int k = 0; k < 16; k += 4) {
          const float4 w = *(const float4*)&W3T[j][k];
          s += h2[k] * w.x + h2[k + 1] * w.y + h2[k + 2] * w.z + h2[k + 3] * w.w;
        }
        out[(size_t)node * 10 + j] = s;
      }
    }
  }
}

extern "C" void kernel_launch(void* const* d_in, const int* in_sizes, int n_in,
                              void* d_out, int out_size, void* d_ws, size_t ws_size,
                              hipStream_t stream) {
  const float* x     = (const float*)d_in[0];
  const int*   ei    = (const int*)d_in[1];
  const float* W_gcn = (const float*)d_in[2];
  const float* b_gcn = (const float*)d_in[3];
  const float* W1    = (const float*)d_in[4];
  const float* b1    = (const float*)d_in[5];
  const float* W2    = (const float*)d_in[6];
  const float* b2    = (const float*)d_in[7];
  const float* W3    = (const float*)d_in[8];
  const float* b3    = (const float*)d_in[9];
  float* out = (float*)d_out;

  const int N = in_sizes[0] / F_IN;   // 100000
  const int E = in_sizes[1] / 2;      // 3200000
  const int* src = ei;
  const int* dst = ei + E;
  const int NBK = (N + 255) >> 8;     // 391 buckets of 256 nodes
  const int NBLK_E = (E + SC_CHUNK - 1) / SC_CHUNK;

  int2*  es2         = (int2*)d_ws;                       // E int2
  float* h           = (float*)(es2 + (size_t)E);         // N*64 f
  float* dinvp       = h + (size_t)N * 64;                // N f
  int*   bucketCount = (int*)(dinvp + N);                 // 512 i
  int*   bucketStart = bucketCount + 512;                 // 513 i
  int*   bucketCursor= bucketStart + 513;                 // 512 i

  hipMemsetAsync(bucketCount, 0, 512 * sizeof(int), stream);

  gemm_xw_kernel<<<(N + 63) / 64, 256, 0, stream>>>(x, W_gcn, h, N);

  hist_coarse_kernel<<<NBLK_E, 256, 0, stream>>>(dst, bucketCount, E, NBK);
  scan_buckets_kernel<<<1, 512, 0, stream>>>(bucketCount, bucketStart, bucketCursor, NBK);
  scatter_coarse_kernel<<<NBLK_E, 256, 0, stream>>>(src, dst, bucketCursor, es2, E, NBK);
  deg_fine_kernel<<<NBK, 256, 0, stream>>>(es2, bucketStart, dinvp, N);

  agg_mlp_kernel<<<NBK, 512, 0, stream>>>(
      h, es2, bucketStart, dinvp, b_gcn, W1, b1, W2, b2, W3, b3, out, N);
}

// Round 4
// 458.057 us; speedup vs baseline: 3.6556x; 3.6556x over previous
//
#include <hip/hip_runtime.h>

#define F_IN 256
#define SC_CHUNK 16384

// ---------------- GEMM: h = x @ W  (M x 256) @ (256 x 64) -> (M x 64) --------
__global__ __launch_bounds__(256) void gemm_xw_kernel(
    const float* __restrict__ x, const float* __restrict__ W,
    float* __restrict__ h, int M) {
  __shared__ float As[32][68];
  __shared__ float Bs[32][64];
  const int t = threadIdx.x;
  const int brow = blockIdx.x * 64;
  const int tc = t & 15;
  const int tr = t >> 4;
  float acc[4][4] = {{0.f}};

  for (int k0 = 0; k0 < F_IN; k0 += 32) {
    {
      const int m = t >> 3;
      const int kq = (t & 7) << 2;
#pragma unroll
      for (int half = 0; half < 2; ++half) {
        const int mm = m + half * 32;
        const int row = brow + mm;
        float4 v = make_float4(0.f, 0.f, 0.f, 0.f);
        if (row < M) v = *(const float4*)(x + (size_t)row * F_IN + k0 + kq);
        As[kq + 0][mm] = v.x;
        As[kq + 1][mm] = v.y;
        As[kq + 2][mm] = v.z;
        As[kq + 3][mm] = v.w;
      }
#pragma unroll
      for (int half = 0; half < 2; ++half) {
        const int i = t + half * 256;
        const int kb = i >> 4;
        const int nq = (i & 15) << 2;
        *(float4*)&Bs[kb][nq] = *(const float4*)(W + (size_t)(k0 + kb) * 64 + nq);
      }
    }
    __syncthreads();
#pragma unroll
    for (int k = 0; k < 32; ++k) {
      const float4 a = *(const float4*)&As[k][tr << 2];
      const float4 b = *(const float4*)&Bs[k][tc << 2];
      const float av[4] = {a.x, a.y, a.z, a.w};
      const float bv[4] = {b.x, b.y, b.z, b.w};
#pragma unroll
      for (int i = 0; i < 4; ++i)
#pragma unroll
        for (int j = 0; j < 4; ++j) acc[i][j] += av[i] * bv[j];
    }
    __syncthreads();
  }
#pragma unroll
  for (int i = 0; i < 4; ++i) {
    const int row = brow + (tr << 2) + i;
    if (row < M) {
      float4 v = make_float4(acc[i][0], acc[i][1], acc[i][2], acc[i][3]);
      *(float4*)(h + (size_t)row * 64 + (tc << 2)) = v;
    }
  }
}

// ---------------- coarse histogram over dst>>8 -------------------------------
__global__ __launch_bounds__(256) void hist_coarse_kernel(
    const int* __restrict__ dst_arr, int* __restrict__ bucketCount,
    int E, int NBK) {
  __shared__ int hist[512];
  const int t = threadIdx.x;
  for (int i = t; i < NBK; i += 256) hist[i] = 0;
  __syncthreads();
  const int base = blockIdx.x * SC_CHUNK;
  const int end = min(base + SC_CHUNK, E);
  for (int i = base + t; i < end; i += 256)
    atomicAdd(&hist[dst_arr[i] >> 8], 1);
  __syncthreads();
  for (int i = t; i < NBK; i += 256)
    if (hist[i]) atomicAdd(&bucketCount[i], hist[i]);
}

// ---------------- scan bucket counts (NBK <= 512) ----------------------------
__global__ __launch_bounds__(512) void scan_buckets_kernel(
    const int* __restrict__ bucketCount, int* __restrict__ bucketStart,
    int* __restrict__ bucketCursor, int NBK) {
  __shared__ int s[512];
  const int t = threadIdx.x;
  const int v = (t < NBK) ? bucketCount[t] : 0;
  s[t] = v;
  __syncthreads();
#pragma unroll
  for (int off = 1; off < 512; off <<= 1) {
    int add = (t >= off) ? s[t - off] : 0;
    __syncthreads();
    s[t] += add;
    __syncthreads();
  }
  if (t < NBK) {
    const int excl = s[t] - v;
    bucketStart[t] = excl;
    bucketCursor[t] = excl;
  }
  if (t == NBK - 1) bucketStart[NBK] = s[t];
}

// ---------------- coarse scatter: es2 grouped by bucket ----------------------
__global__ __launch_bounds__(256) void scatter_coarse_kernel(
    const int* __restrict__ src_arr, const int* __restrict__ dst_arr,
    int* __restrict__ bucketCursor, int2* __restrict__ es2, int E, int NBK) {
  __shared__ int hist[512];
  __shared__ int cur[512];
  const int t = threadIdx.x;
  for (int i = t; i < NBK; i += 256) hist[i] = 0;
  __syncthreads();
  const int base = blockIdx.x * SC_CHUNK;
  const int end = min(base + SC_CHUNK, E);
  for (int i = base + t; i < end; i += 256)
    atomicAdd(&hist[dst_arr[i] >> 8], 1);
  __syncthreads();
  for (int i = t; i < NBK; i += 256)
    cur[i] = hist[i] ? atomicAdd(&bucketCursor[i], hist[i]) : 0;
  __syncthreads();
  for (int i = base + t; i < end; i += 256) {
    const int s = src_arr[i];
    const int d = dst_arr[i];
    const int pos = atomicAdd(&cur[d >> 8], 1);
    es2[pos] = make_int2(s, d);
  }
}

// ------ per-bucket fine bin: CSR rowptr + sorted es + dinvp ------------------
__global__ __launch_bounds__(256) void fine_bin_kernel(
    const int2* __restrict__ es2, const int* __restrict__ bucketStart,
    int* __restrict__ es, int* __restrict__ rowptr, float* __restrict__ dinvp,
    int N, int E) {
  __shared__ int hist[256];
  __shared__ int s[256];
  __shared__ int cur[256];
  const int t = threadIdx.x;
  hist[t] = 0;
  __syncthreads();
  const int b = blockIdx.x;
  const int start = bucketStart[b], end = bucketStart[b + 1];
  for (int i = start + t; i < end; i += 256)
    atomicAdd(&hist[es2[i].y & 255], 1);
  __syncthreads();
  const int v = hist[t];
  s[t] = v;
  __syncthreads();
#pragma unroll
  for (int off = 1; off < 256; off <<= 1) {
    int add = (t >= off) ? s[t - off] : 0;
    __syncthreads();
    s[t] += add;
    __syncthreads();
  }
  const int excl = s[t] - v;
  cur[t] = start + excl;
  const int node = b * 256 + t;
  if (node < N) {
    rowptr[node] = start + excl;
    dinvp[node] = rsqrtf((float)(v + 1));  // +1 self-loop
  }
  if (b == gridDim.x - 1 && t == 255) rowptr[N] = E;
  __syncthreads();
  for (int i = start + t; i < end; i += 256) {
    const int2 e = es2[i];
    const int pos = atomicAdd(&cur[e.y & 255], 1);
    es[pos] = e.x;
  }
}

// ---------------- CSR aggregation: one wave per node -------------------------
__global__ __launch_bounds__(256) void agg_csr_kernel(
    const float* __restrict__ h, const int* __restrict__ es,
    const int* __restrict__ rowptr, const float* __restrict__ dinvp,
    float* __restrict__ agg, int N) {
  const int t = threadIdx.x;
  const int node = blockIdx.x * 4 + (t >> 6);
  if (node >= N) return;
  const int lane = t & 63;
  const int slot = lane >> 4;        // 0..3 : edge slot
  const int q = (lane & 15) << 2;    // feature quad
  const int start = rowptr[node];
  const int end = rowptr[node + 1];

  float4 acc = make_float4(0.f, 0.f, 0.f, 0.f);
  int i = start + slot;
  // unroll 2: keep 2 gathers in flight per slot (8 per wave)
  for (; i + 4 < end; i += 8) {
    const int s0 = es[i];
    const int s1 = es[i + 4];
    const float w0 = dinvp[s0];
    const float w1 = dinvp[s1];
    const float4 v0 = *(const float4*)(h + (size_t)s0 * 64 + q);
    const float4 v1 = *(const float4*)(h + (size_t)s1 * 64 + q);
    acc.x += w0 * v0.x + w1 * v1.x;
    acc.y += w0 * v0.y + w1 * v1.y;
    acc.z += w0 * v0.z + w1 * v1.z;
    acc.w += w0 * v0.w + w1 * v1.w;
  }
  if (i < end) {
    const int s0 = es[i];
    const float w0 = dinvp[s0];
    const float4 v0 = *(const float4*)(h + (size_t)s0 * 64 + q);
    acc.x += w0 * v0.x;
    acc.y += w0 * v0.y;
    acc.z += w0 * v0.z;
    acc.w += w0 * v0.w;
  }
  acc.x += __shfl_xor(acc.x, 16, 64);
  acc.y += __shfl_xor(acc.y, 16, 64);
  acc.z += __shfl_xor(acc.z, 16, 64);
  acc.w += __shfl_xor(acc.w, 16, 64);
  acc.x += __shfl_xor(acc.x, 32, 64);
  acc.y += __shfl_xor(acc.y, 32, 64);
  acc.z += __shfl_xor(acc.z, 32, 64);
  acc.w += __shfl_xor(acc.w, 32, 64);

  if (slot == 0) {
    const float wd = dinvp[node];
    float4 o = make_float4(acc.x * wd, acc.y * wd, acc.z * wd, acc.w * wd);
    *(float4*)(agg + (size_t)node * 64 + q) = o;
  }
}

// ---------------- fused epilogue + MLP ---------------------------------------
__global__ __launch_bounds__(256) void mlp_kernel(
    const float* __restrict__ agg, const float* __restrict__ h,
    const float* __restrict__ dinvp, const float* __restrict__ bg,
    const float* __restrict__ W1, const float* __restrict__ b1,
    const float* __restrict__ W2, const float* __restrict__ b2,
    const float* __restrict__ W3, const float* __restrict__ b3,
    float* __restrict__ out, int N) {
  __shared__ float W1T[32][64];
  __shared__ float W2T[16][32];
  __shared__ float W3T[10][16];
  __shared__ float b1s[32], b2s[16], b3s[10], bgs[64];
  const int t = threadIdx.x;
  for (int i = t; i < 2048; i += 256) W1T[i >> 6][i & 63] = W1[(i & 63) * 32 + (i >> 6)];
  for (int i = t; i < 512; i += 256)  W2T[i >> 5][i & 31] = W2[(i & 31) * 16 + (i >> 5)];
  for (int i = t; i < 160; i += 256)  W3T[i >> 4][i & 15] = W3[(i & 15) * 10 + (i >> 4)];
  if (t < 64) bgs[t] = bg[t];
  if (t < 32) b1s[t] = b1[t];
  if (t < 16) b2s[t] = b2[t];
  if (t < 10) b3s[t] = b3[t];
  __syncthreads();

  const int node = blockIdx.x * 256 + t;
  if (node >= N) return;
  const float di = dinvp[node];
  const float d2 = di * di;

  float g[64];
#pragma unroll
  for (int k = 0; k < 64; k += 4) {
    const float4 a = *(const float4*)(agg + (size_t)node * 64 + k);
    const float4 hv = *(const float4*)(h + (size_t)node * 64 + k);
    g[k + 0] = fmaxf(a.x + d2 * hv.x + bgs[k + 0], 0.f);
    g[k + 1] = fmaxf(a.y + d2 * hv.y + bgs[k + 1], 0.f);
    g[k + 2] = fmaxf(a.z + d2 * hv.z + bgs[k + 2], 0.f);
    g[k + 3] = fmaxf(a.w + d2 * hv.w + bgs[k + 3], 0.f);
  }

  float h1[32];
#pragma unroll
  for (int j = 0; j < 32; ++j) {
    float acc = b1s[j];
#pragma unroll
    for (int k = 0; k < 64; k += 4) {
      const float4 w = *(const float4*)&W1T[j][k];
      acc += g[k] * w.x + g[k + 1] * w.y + g[k + 2] * w.z + g[k + 3] * w.w;
    }
    h1[j] = fmaxf(acc, 0.f);
  }

  float h2[16];
#pragma unroll
  for (int j = 0; j < 16; ++j) {
    float acc = b2s[j];
#pragma unroll
    for (int k = 0; k < 32; k += 4) {
      const float4 w = *(const float4*)&W2T[j][k];
      acc += h1[k] * w.x + h1[k + 1] * w.y + h1[k + 2] * w.z + h1[k + 3] * w.w;
    }
    h2[j] = fmaxf(acc, 0.f);
  }

#pragma unroll
  for (int j = 0; j < 10; ++j) {
    float acc = b3s[j];
#pragma unroll
    for (int k = 0; k < 16; k += 4) {
      const float4 w = *(const float4*)&W3T[j][k];
      acc += h2[k] * w.x + h2[k + 1] * w.y + h2[k + 2] * w.z + h2[k + 3] * w.w;
    }
    out[(size_t)node * 10 + j] = acc;
  }
}

extern "C" void kernel_launch(void* const* d_in, const int* in_sizes, int n_in,
                              void* d_out, int out_size, void* d_ws, size_t ws_size,
                              hipStream_t stream) {
  const float* x     = (const float*)d_in[0];
  const int*   ei    = (const int*)d_in[1];
  const float* W_gcn = (const float*)d_in[2];
  const float* b_gcn = (const float*)d_in[3];
  const float* W1    = (const float*)d_in[4];
  const float* b1    = (const float*)d_in[5];
  const float* W2    = (const float*)d_in[6];
  const float* b2    = (const float*)d_in[7];
  const float* W3    = (const float*)d_in[8];
  const float* b3    = (const float*)d_in[9];
  float* out = (float*)d_out;

  const int N = in_sizes[0] / F_IN;   // 100000
  const int E = in_sizes[1] / 2;      // 3200000
  const int* src = ei;
  const int* dst = ei + E;
  const int NBK = (N + 255) >> 8;     // 391 buckets of 256 nodes
  const int NBLK_E = (E + SC_CHUNK - 1) / SC_CHUNK;

  // es2 (E int2 = 25.6 MB) is dead after fine_bin; agg (N*64 f = 25.6 MB)
  // aliases it.
  int2*  es2         = (int2*)d_ws;                       // E int2
  float* agg         = (float*)d_ws;                      // N*64 f (alias)
  float* h           = (float*)(es2 + (size_t)E);         // N*64 f
  float* dinvp       = h + (size_t)N * 64;                // N f
  int*   es          = (int*)(dinvp + N);                 // E i
  int*   rowptr      = es + E;                            // N+1 i
  int*   bucketCount = rowptr + N + 1;                    // 512 i
  int*   bucketStart = bucketCount + 512;                 // 513 i
  int*   bucketCursor= bucketStart + 513;                 // 512 i

  hipMemsetAsync(bucketCount, 0, 512 * sizeof(int), stream);

  gemm_xw_kernel<<<(N + 63) / 64, 256, 0, stream>>>(x, W_gcn, h, N);

  hist_coarse_kernel<<<NBLK_E, 256, 0, stream>>>(dst, bucketCount, E, NBK);
  scan_buckets_kernel<<<1, 512, 0, stream>>>(bucketCount, bucketStart, bucketCursor, NBK);
  scatter_coarse_kernel<<<NBLK_E, 256, 0, stream>>>(src, dst, bucketCursor, es2, E, NBK);
  fine_bin_kernel<<<NBK, 256, 0, stream>>>(es2, bucketStart, es, rowptr, dinvp, N, E);

  agg_csr_kernel<<<(N + 3) / 4, 256, 0, stream>>>(h, es, rowptr, dinvp, agg, N);

  mlp_kernel<<<(N + 255) / 256, 256, 0, stream>>>(
      agg, h, dinvp, b_gcn, W1, b1, W2, b2, W3, b3, out, N);
}

// Round 5
// 391.939 us; speedup vs baseline: 4.2723x; 1.1687x over previous
//
#include <hip/hip_runtime.h>

#define F_IN 256
#define SC_CHUNK 16384

__device__ __forceinline__ unsigned short f2bf(float f) {
  unsigned u = __float_as_uint(f);
  unsigned r = (u + 0x7FFFu + ((u >> 16) & 1u)) >> 16;  // RNE
  return (unsigned short)r;
}
#define BF_LO(d) __uint_as_float((d) << 16)
#define BF_HI(d) __uint_as_float((d) & 0xFFFF0000u)

// ------- GEMM: hb = bf16(dinv[row] * (x @ W))  (M x 256)@(256 x 64) ----------
__global__ __launch_bounds__(256) void gemm_xw_kernel(
    const float* __restrict__ x, const float* __restrict__ W,
    const float* __restrict__ dinvp, unsigned short* __restrict__ hb, int M) {
  __shared__ float As[32][68];
  __shared__ float Bs[32][64];
  const int t = threadIdx.x;
  const int brow = blockIdx.x * 64;
  const int tc = t & 15;
  const int tr = t >> 4;
  float acc[4][4] = {{0.f}};

  for (int k0 = 0; k0 < F_IN; k0 += 32) {
    {
      const int m = t >> 3;
      const int kq = (t & 7) << 2;
#pragma unroll
      for (int half = 0; half < 2; ++half) {
        const int mm = m + half * 32;
        const int row = brow + mm;
        float4 v = make_float4(0.f, 0.f, 0.f, 0.f);
        if (row < M) v = *(const float4*)(x + (size_t)row * F_IN + k0 + kq);
        As[kq + 0][mm] = v.x;
        As[kq + 1][mm] = v.y;
        As[kq + 2][mm] = v.z;
        As[kq + 3][mm] = v.w;
      }
#pragma unroll
      for (int half = 0; half < 2; ++half) {
        const int i = t + half * 256;
        const int kb = i >> 4;
        const int nq = (i & 15) << 2;
        *(float4*)&Bs[kb][nq] = *(const float4*)(W + (size_t)(k0 + kb) * 64 + nq);
      }
    }
    __syncthreads();
#pragma unroll
    for (int k = 0; k < 32; ++k) {
      const float4 a = *(const float4*)&As[k][tr << 2];
      const float4 b = *(const float4*)&Bs[k][tc << 2];
      const float av[4] = {a.x, a.y, a.z, a.w};
      const float bv[4] = {b.x, b.y, b.z, b.w};
#pragma unroll
      for (int i = 0; i < 4; ++i)
#pragma unroll
        for (int j = 0; j < 4; ++j) acc[i][j] += av[i] * bv[j];
    }
    __syncthreads();
  }
#pragma unroll
  for (int i = 0; i < 4; ++i) {
    const int row = brow + (tr << 2) + i;
    if (row < M) {
      const float di = dinvp[row];
      ushort4 o;
      o.x = f2bf(di * acc[i][0]);
      o.y = f2bf(di * acc[i][1]);
      o.z = f2bf(di * acc[i][2]);
      o.w = f2bf(di * acc[i][3]);
      *(ushort4*)(hb + (size_t)row * 64 + (tc << 2)) = o;
    }
  }
}

// ---------------- coarse histogram over dst>>8 -------------------------------
__global__ __launch_bounds__(256) void hist_coarse_kernel(
    const int* __restrict__ dst_arr, int* __restrict__ bucketCount,
    int E, int NBK) {
  __shared__ int hist[512];
  const int t = threadIdx.x;
  for (int i = t; i < NBK; i += 256) hist[i] = 0;
  __syncthreads();
  const int base = blockIdx.x * SC_CHUNK;
  const int end = min(base + SC_CHUNK, E);
  for (int i = base + t; i < end; i += 256)
    atomicAdd(&hist[dst_arr[i] >> 8], 1);
  __syncthreads();
  for (int i = t; i < NBK; i += 256)
    if (hist[i]) atomicAdd(&bucketCount[i], hist[i]);
}

// ---------------- scan bucket counts (NBK <= 512) ----------------------------
__global__ __launch_bounds__(512) void scan_buckets_kernel(
    const int* __restrict__ bucketCount, int* __restrict__ bucketStart,
    int* __restrict__ bucketCursor, int NBK) {
  __shared__ int s[512];
  const int t = threadIdx.x;
  const int v = (t < NBK) ? bucketCount[t] : 0;
  s[t] = v;
  __syncthreads();
#pragma unroll
  for (int off = 1; off < 512; off <<= 1) {
    int add = (t >= off) ? s[t - off] : 0;
    __syncthreads();
    s[t] += add;
    __syncthreads();
  }
  if (t < NBK) {
    const int excl = s[t] - v;
    bucketStart[t] = excl;
    bucketCursor[t] = excl;
  }
  if (t == NBK - 1) bucketStart[NBK] = s[t];
}

// ------- coarse scatter: esp grouped by bucket, packed src|(dst&255)<<24 -----
__global__ __launch_bounds__(256) void scatter_coarse_kernel(
    const int* __restrict__ src_arr, const int* __restrict__ dst_arr,
    int* __restrict__ bucketCursor, int* __restrict__ esp, int E, int NBK) {
  __shared__ int hist[512];
  __shared__ int cur[512];
  const int t = threadIdx.x;
  for (int i = t; i < NBK; i += 256) hist[i] = 0;
  __syncthreads();
  const int base = blockIdx.x * SC_CHUNK;
  const int end = min(base + SC_CHUNK, E);
  for (int i = base + t; i < end; i += 256)
    atomicAdd(&hist[dst_arr[i] >> 8], 1);
  __syncthreads();
  for (int i = t; i < NBK; i += 256)
    cur[i] = hist[i] ? atomicAdd(&bucketCursor[i], hist[i]) : 0;
  __syncthreads();
  for (int i = base + t; i < end; i += 256) {
    const int s = src_arr[i];
    const int d = dst_arr[i];
    const int pos = atomicAdd(&cur[d >> 8], 1);
    esp[pos] = s | ((d & 255) << 24);
  }
}

// ------ per-bucket fine bin: CSR rowptr + sorted es + dinvp ------------------
__global__ __launch_bounds__(256) void fine_bin_kernel(
    const int* __restrict__ esp, const int* __restrict__ bucketStart,
    int* __restrict__ es, int* __restrict__ rowptr, float* __restrict__ dinvp,
    int N, int E) {
  __shared__ int hist[256];
  __shared__ int s[256];
  __shared__ int cur[256];
  const int t = threadIdx.x;
  hist[t] = 0;
  __syncthreads();
  const int b = blockIdx.x;
  const int start = bucketStart[b], end = bucketStart[b + 1];
  for (int i = start + t; i < end; i += 256)
    atomicAdd(&hist[((unsigned)esp[i]) >> 24], 1);
  __syncthreads();
  const int v = hist[t];
  s[t] = v;
  __syncthreads();
#pragma unroll
  for (int off = 1; off < 256; off <<= 1) {
    int add = (t >= off) ? s[t - off] : 0;
    __syncthreads();
    s[t] += add;
    __syncthreads();
  }
  const int excl = s[t] - v;
  cur[t] = start + excl;
  const int node = b * 256 + t;
  if (node < N) {
    rowptr[node] = start + excl;
    dinvp[node] = rsqrtf((float)(v + 1));  // +1 self-loop
  }
  if (b == gridDim.x - 1 && t == 255) rowptr[N] = E;
  __syncthreads();
  for (int i = start + t; i < end; i += 256) {
    const int p = esp[i];
    const int pos = atomicAdd(&cur[((unsigned)p) >> 24], 1);
    es[pos] = p & 0x00FFFFFF;
  }
}

// ------- CSR aggregation: one wave per node, bf16 pre-scaled gather ----------
__global__ __launch_bounds__(256) void agg_csr_kernel(
    const unsigned short* __restrict__ hb, const int* __restrict__ es,
    const int* __restrict__ rowptr, const float* __restrict__ dinvp,
    float* __restrict__ agg, int N) {
  const int t = threadIdx.x;
  const int node = blockIdx.x * 4 + (t >> 6);
  if (node >= N) return;
  const int lane = t & 63;
  const int slot = lane >> 3;        // 0..7 : edge slot
  const int fq = (lane & 7) << 3;    // feature base (8 feats, 16 B)
  const int start = rowptr[node];
  const int end = rowptr[node + 1];

  float acc[8] = {0.f};
  int i = start + slot;
  for (; i + 8 < end; i += 16) {
    const int s0 = es[i];
    const int s1 = es[i + 8];
    const uint4 r0 = *(const uint4*)(hb + (size_t)s0 * 64 + fq);
    const uint4 r1 = *(const uint4*)(hb + (size_t)s1 * 64 + fq);
    acc[0] += BF_LO(r0.x) + BF_LO(r1.x);
    acc[1] += BF_HI(r0.x) + BF_HI(r1.x);
    acc[2] += BF_LO(r0.y) + BF_LO(r1.y);
    acc[3] += BF_HI(r0.y) + BF_HI(r1.y);
    acc[4] += BF_LO(r0.z) + BF_LO(r1.z);
    acc[5] += BF_HI(r0.z) + BF_HI(r1.z);
    acc[6] += BF_LO(r0.w) + BF_LO(r1.w);
    acc[7] += BF_HI(r0.w) + BF_HI(r1.w);
  }
  if (i < end) {
    const int s0 = es[i];
    const uint4 r0 = *(const uint4*)(hb + (size_t)s0 * 64 + fq);
    acc[0] += BF_LO(r0.x);
    acc[1] += BF_HI(r0.x);
    acc[2] += BF_LO(r0.y);
    acc[3] += BF_HI(r0.y);
    acc[4] += BF_LO(r0.z);
    acc[5] += BF_HI(r0.z);
    acc[6] += BF_LO(r0.w);
    acc[7] += BF_HI(r0.w);
  }
#pragma unroll
  for (int m = 8; m <= 32; m <<= 1)
#pragma unroll
    for (int j = 0; j < 8; ++j) acc[j] += __shfl_xor(acc[j], m, 64);

  if (slot == 0) {
    const float di = dinvp[node];
    float4 o0 = make_float4(acc[0] * di, acc[1] * di, acc[2] * di, acc[3] * di);
    float4 o1 = make_float4(acc[4] * di, acc[5] * di, acc[6] * di, acc[7] * di);
    float* ap = agg + (size_t)node * 64 + fq;
    *(float4*)(ap + 0) = o0;
    *(float4*)(ap + 4) = o1;
  }
}

// ---------------- fused epilogue + MLP ---------------------------------------
__global__ __launch_bounds__(256) void mlp_kernel(
    const float* __restrict__ agg, const unsigned short* __restrict__ hb,
    const float* __restrict__ dinvp, const float* __restrict__ bg,
    const float* __restrict__ W1, const float* __restrict__ b1,
    const float* __restrict__ W2, const float* __restrict__ b2,
    const float* __restrict__ W3, const float* __restrict__ b3,
    float* __restrict__ out, int N) {
  __shared__ float W1T[32][64];
  __shared__ float W2T[16][32];
  __shared__ float W3T[10][16];
  __shared__ float b1s[32], b2s[16], b3s[10], bgs[64];
  const int t = threadIdx.x;
  for (int i = t; i < 2048; i += 256) W1T[i >> 6][i & 63] = W1[(i & 63) * 32 + (i >> 6)];
  for (int i = t; i < 512; i += 256)  W2T[i >> 5][i & 31] = W2[(i & 31) * 16 + (i >> 5)];
  for (int i = t; i < 160; i += 256)  W3T[i >> 4][i & 15] = W3[(i & 15) * 10 + (i >> 4)];
  if (t < 64) bgs[t] = bg[t];
  if (t < 32) b1s[t] = b1[t];
  if (t < 16) b2s[t] = b2[t];
  if (t < 10) b3s[t] = b3[t];
  __syncthreads();

  const int node = blockIdx.x * 256 + t;
  if (node >= N) return;
  const float di = dinvp[node];

  float g[64];
#pragma unroll
  for (int k = 0; k < 64; k += 8) {
    const float4 a0 = *(const float4*)(agg + (size_t)node * 64 + k);
    const float4 a1 = *(const float4*)(agg + (size_t)node * 64 + k + 4);
    const uint4 r = *(const uint4*)(hb + (size_t)node * 64 + k);
    g[k + 0] = fmaxf(a0.x + di * BF_LO(r.x) + bgs[k + 0], 0.f);
    g[k + 1] = fmaxf(a0.y + di * BF_HI(r.x) + bgs[k + 1], 0.f);
    g[k + 2] = fmaxf(a0.z + di * BF_LO(r.y) + bgs[k + 2], 0.f);
    g[k + 3] = fmaxf(a0.w + di * BF_HI(r.y) + bgs[k + 3], 0.f);
    g[k + 4] = fmaxf(a1.x + di * BF_LO(r.z) + bgs[k + 4], 0.f);
    g[k + 5] = fmaxf(a1.y + di * BF_HI(r.z) + bgs[k + 5], 0.f);
    g[k + 6] = fmaxf(a1.z + di * BF_LO(r.w) + bgs[k + 6], 0.f);
    g[k + 7] = fmaxf(a1.w + di * BF_HI(r.w) + bgs[k + 7], 0.f);
  }

  float h1[32];
#pragma unroll
  for (int j = 0; j < 32; ++j) {
    float acc = b1s[j];
#pragma unroll
    for (int k = 0; k < 64; k += 4) {
      const float4 w = *(const float4*)&W1T[j][k];
      acc += g[k] * w.x + g[k + 1] * w.y + g[k + 2] * w.z + g[k + 3] * w.w;
    }
    h1[j] = fmaxf(acc, 0.f);
  }

  float h2[16];
#pragma unroll
  for (int j = 0; j < 16; ++j) {
    float acc = b2s[j];
#pragma unroll
    for (int k = 0; k < 32; k += 4) {
      const float4 w = *(const float4*)&W2T[j][k];
      acc += h1[k] * w.x + h1[k + 1] * w.y + h1[k + 2] * w.z + h1[k + 3] * w.w;
    }
    h2[j] = fmaxf(acc, 0.f);
  }

#pragma unroll
  for (int j = 0; j < 10; ++j) {
    float acc = b3s[j];
#pragma unroll
    for (int k = 0; k < 16; k += 4) {
      const float4 w = *(const float4*)&W3T[j][k];
      acc += h2[k] * w.x + h2[k + 1] * w.y + h2[k + 2] * w.z + h2[k + 3] * w.w;
    }
    out[(size_t)node * 10 + j] = acc;
  }
}

extern "C" void kernel_launch(void* const* d_in, const int* in_sizes, int n_in,
                              void* d_out, int out_size, void* d_ws, size_t ws_size,
                              hipStream_t stream) {
  const float* x     = (const float*)d_in[0];
  const int*   ei    = (const int*)d_in[1];
  const float* W_gcn = (const float*)d_in[2];
  const float* b_gcn = (const float*)d_in[3];
  const float* W1    = (const float*)d_in[4];
  const float* b1    = (const float*)d_in[5];
  const float* W2    = (const float*)d_in[6];
  const float* b2    = (const float*)d_in[7];
  const float* W3    = (const float*)d_in[8];
  const float* b3    = (const float*)d_in[9];
  float* out = (float*)d_out;

  const int N = in_sizes[0] / F_IN;   // 100000
  const int E = in_sizes[1] / 2;      // 3200000
  const int* src = ei;
  const int* dst = ei + E;
  const int NBK = (N + 255) >> 8;     // 391 buckets of 256 nodes
  const int NBLK_E = (E + SC_CHUNK - 1) / SC_CHUNK;

  // Layout (~52 MB): esp (E int, dead after fine_bin) aliased by agg (N*64 f).
  unsigned short* hb = (unsigned short*)d_ws;            // N*64 us  (12.8 MB)
  float* dinvp       = (float*)(hb + (size_t)N * 64);    // N f
  int*   es          = (int*)(dinvp + N);                // E i      (12.8 MB)
  int*   rowptr      = es + E;                           // N+16 i
  int*   bucketCount = rowptr + N + 16;                  // 512 i
  int*   bucketStart = bucketCount + 512;                // 528 i
  int*   bucketCursor= bucketStart + 528;                // 512 i
  int*   esp         = bucketCursor + 512;               // E i      (12.8 MB)
  float* agg         = (float*)esp;                      // N*64 f (25.6 MB alias)

  hipMemsetAsync(bucketCount, 0, 512 * sizeof(int), stream);

  hist_coarse_kernel<<<NBLK_E, 256, 0, stream>>>(dst, bucketCount, E, NBK);
  scan_buckets_kernel<<<1, 512, 0, stream>>>(bucketCount, bucketStart, bucketCursor, NBK);
  scatter_coarse_kernel<<<NBLK_E, 256, 0, stream>>>(src, dst, bucketCursor, esp, E, NBK);
  fine_bin_kernel<<<NBK, 256, 0, stream>>>(esp, bucketStart, es, rowptr, dinvp, N, E);

  gemm_xw_kernel<<<(N + 63) / 64, 256, 0, stream>>>(x, W_gcn, dinvp, hb, N);

  agg_csr_kernel<<<(N + 3) / 4, 256, 0, stream>>>(hb, es, rowptr, dinvp, agg, N);

  mlp_kernel<<<(N + 255) / 256, 256, 0, stream>>>(
      agg, hb, dinvp, b_gcn, W1, b1, W2, b2, W3, b3, out, N);
}